// Round 24
// baseline (132.844 us; speedup 1.0000x reference)
//
#include <hip/hip_runtime.h>

#define NPROP 8192
#define NT 1024
typedef unsigned long long u64;

__device__ __forceinline__ int bucket_of(float s) {
    int b = (int)(s * 8192.0f);   // exact: *2^13 is an exponent shift
    return b < 0 ? 0 : (b > NPROP - 1 ? NPROP - 1 : b);
}

__device__ __forceinline__ bool iou_gt_thr(float4 a, float4 b) {
    float areaA = (a.z - a.x) * (a.w - a.y);
    float areaB = (b.z - b.x) * (b.w - b.y);
    float lx = fmaxf(a.x, b.x), ly = fmaxf(a.y, b.y);
    float rx = fminf(a.z, b.z), ry = fminf(a.w, b.w);
    float w = fmaxf(rx - lx, 0.0f), h = fmaxf(ry - ly, 0.0f);
    float inter = w * h;
    float uni = areaA + areaB - inter;
    float iou = inter / fmaxf(uni, 1e-6f);
    return iou > 0.3f;
}

// LDS carve (dynamic, 100880 B):
//   [0,32768)       hist (int[8192])  -> reused as klidx after rank phase
//   [32768,65536)   pref (unsigned[8192]) packed all|valid<<16
//   [65536,98304)   tmp  (int[8192])  validity-tagged bucket-grouped indices
//   [98304,99328)   rem  (u64[128])
//   [99328,100352)  diagb(u64[2][64])
//   [100352,100864) nextw(u64[64])
//   [100864,100880) pullw(u64[2])
#define SMEM_BYTES 100880

__global__ __launch_bounds__(NT)
void k_all(const float* __restrict__ boxes, const float* __restrict__ scores,
           const float* __restrict__ img,
           float4* __restrict__ cbox, float* __restrict__ cscore,
           int* __restrict__ vrank, float* __restrict__ out) {
    extern __shared__ char smem[];
    int*      hist  = (int*)smem;
    unsigned* pref  = (unsigned*)(smem + 32768);
    int*      tmp   = (int*)(smem + 65536);
    u64*      rem   = (u64*)(smem + 98304);
    u64*      diagb = (u64*)(smem + 99328);
    u64*      nextw = (u64*)(smem + 100352);
    u64*      pullw = (u64*)(smem + 100864);
    int*      klidx = hist;                 // alias: hist dead after rank
    __shared__ int wsum[16], wexcl[16];
    __shared__ int metaV[4];
    __shared__ int Ksh;

    const int tid = threadIdx.x, lane = tid & 63, wave = tid >> 6;

    // ---- P0: zero out (fire-and-forget) + zero hist ----
    float4 z4 = make_float4(0.f, 0.f, 0.f, 0.f);
    #pragma unroll
    for (int q = 0; q < 12; q++)
        reinterpret_cast<float4*>(out)[q * NT + tid] = z4;   // 12288 float4 total
    #pragma unroll
    for (int u = 0; u < 8; u++) hist[tid * 8 + u] = 0;
    __syncthreads();

    // ---- P1: load own 8 proposals, validity, packed histogram ----
    float ix1 = img[0], iy1 = img[1], ix2 = img[2], iy2 = img[3];
    float img_area = (ix2 - ix1) * (iy2 - iy1);
    float ss[8]; int bk[8], vf[8];
    #pragma unroll
    for (int u = 0; u < 8; u++) {
        int p = u * NT + tid;                 // coalesced
        float s = scores[p];
        float4 bx = reinterpret_cast<const float4*>(boxes)[p];
        float w = bx.z - bx.x, h = bx.w - bx.y;
        float ratio = w / (h + 1e-12f);
        bool vs = (ratio > 0.25f) && (ratio < 4.0f);
        float lx = fmaxf(ix1, bx.x), ly = fmaxf(iy1, bx.y);
        float rx = fminf(ix2, bx.z), ry = fminf(iy2, bx.w);
        float iw = fmaxf(rx - lx, 0.0f), ih = fmaxf(ry - ly, 0.0f);
        float iof = (iw * ih) / fmaxf(img_area, 1e-6f);
        ss[u] = s;
        bk[u] = bucket_of(s);
        vf[u] = (vs && (iof > 0.01f) && (s > 0.85f)) ? 1 : 0;
        atomicAdd(&hist[bk[u]], 1 + (vf[u] << 16));
    }
    __syncthreads();

    // ---- P2: packed exclusive scan over 8192 buckets ----
    int h[8]; int tot = 0;
    #pragma unroll
    for (int u = 0; u < 8; u++) { h[u] = hist[tid * 8 + u]; tot += h[u]; }
    int incl = tot;
    #pragma unroll
    for (int off = 1; off < 64; off <<= 1) {
        int n = __shfl_up(incl, off, 64);
        if (lane >= off) incl += n;
    }
    if (lane == 63) wsum[wave] = incl;
    __syncthreads();
    if (tid == 0) {
        int acc = 0;
        #pragma unroll
        for (int w = 0; w < 16; w++) { int t = wsum[w]; wexcl[w] = acc; acc += t; }
        int Vraw = acc >> 16;
        int V = Vraw == 0 ? 1 : Vraw;
        metaV[0] = V; metaV[1] = (V + 63) >> 6; metaV[2] = Vraw;
    }
    __syncthreads();
    int run = wexcl[wave] + (incl - tot);     // packed prefix
    int runA = run & 0xffff;                  // all-count prefix (allocator)
    #pragma unroll
    for (int u = 0; u < 8; u++) { pref[tid * 8 + u] = (unsigned)run; run += h[u]; }
    __syncthreads();   // all hist reads done before overwrite as allocator
    #pragma unroll
    for (int u = 0; u < 8; u++) { hist[tid * 8 + u] = runA; runA += h[u] & 0xffff; }
    __syncthreads();

    // ---- P3: scatter into bucket-grouped LDS order (validity-tagged) ----
    #pragma unroll
    for (int u = 0; u < 8; u++) {
        int slot = atomicAdd(&hist[bk[u]], 1);
        tmp[slot] = (u * NT + tid) | (vf[u] << 31);
    }
    __syncthreads();

    const int V = metaV[0], W = metaV[1], Vraw = metaV[2];

    // ---- P4: rank own proposals; valid ones materialize cbox/cscore/vrank ----
    #pragma unroll
    for (int u = 0; u < 8; u++) {
        int p = u * NT + tid;
        u64 key = ((u64)__float_as_uint(ss[u]) << 32) | (u64)(unsigned)(NPROP - 1 - p);
        int b = bk[u];
        unsigned pb = pref[b];
        int lo = (int)(pb & 0xffffu), vlo = (int)(pb >> 16);
        int hi = (b < NPROP - 1) ? (int)(pref[b + 1] & 0xffffu) : NPROP;
        int cnt = 0, vcnt = 0;
        for (int q = lo; q < hi; q++) {
            int jp = tmp[q];
            int j = jp & 0xffff;
            int vfj = (int)((unsigned)jp >> 31);
            u64 kj = ((u64)__float_as_uint(scores[j]) << 32) | (u64)(unsigned)(NPROP - 1 - j);
            int less = (kj < key) ? 1 : 0;
            cnt += less; vcnt += less & vfj;
        }
        int rank = NPROP - 1 - (lo + cnt);    // descending, stable
        if (vf[u]) {
            int cpos = Vraw - 1 - (vlo + vcnt);
            float4 bx = reinterpret_cast<const float4*>(boxes)[p];
            cbox[cpos] = bx; cscore[cpos] = ss[u]; vrank[cpos] = rank;
        } else if (Vraw == 0 && rank == 0) {  // fallback: keep top-scoring only
            float4 bx = reinterpret_cast<const float4*>(boxes)[p];
            cbox[0] = bx; cscore[0] = ss[u]; vrank[0] = 0;
        }
    }

    // ---- P5: rem init + prologue diag of block 0 (waves 14-15) ----
    for (int w = tid; w < NPROP / 64; w += NT) {
        int b0 = w * 64; u64 m;
        if (b0 >= V) m = ~0ull;
        else if (b0 + 64 <= V) m = 0ull;
        else m = (~0ull) << (V - b0);
        rem[w] = m;
    }
    if (tid == 0) { Ksh = 0; pullw[0] = 0; pullw[1] = 0; }
    __syncthreads();   // cbox/cscore/vrank globally visible within block (same CU)
    if (wave >= 14) {
        int half = wave - 14;
        int col = lane; bool cv = col < V;
        float4 cb; if (cv) cb = cbox[col];
        #pragma unroll 4
        for (int i = half * 32; i < half * 32 + 32; i++) {
            bool ok = false;
            if (i < V) { float4 br = cbox[i]; ok = cv && (lane > i) && iou_gt_thr(br, cb); }
            u64 bal = __ballot(ok);
            if (lane == 0) diagb[i] = bal;    // diagb[0][i]
        }
    }
    __syncthreads();

    // ---- P6: pipelined pull-resolve with on-the-fly IoU mask words ----
    for (int b = 0; b < W; b++) {
        const int rb0 = b << 6;
        const int nb = b + 1;
        const int K = Ksh;            // kept through block b-1 (stable this phase)
        u64 keptb = 0;
        if (wave == 0) {
            // chain(b): kept-only scalar walk (proven)
            u64 d = diagb[(b & 1) * 64 + lane];
            int dlo = (int)(unsigned)(d & 0xffffffffull);
            int dhi = (int)(unsigned)(d >> 32);
            u64 r0 = rem[b] | pullw[b & 1];
            unsigned rl_ = (unsigned)__builtin_amdgcn_readfirstlane((int)(unsigned)(r0 & 0xffffffffull));
            unsigned rh_ = (unsigned)__builtin_amdgcn_readfirstlane((int)(unsigned)(r0 >> 32));
            u64 r = ((u64)rh_ << 32) | (u64)rl_;
            u64 avail = ~r;
            while (avail) {
                int i = (int)__builtin_ctzll(avail);
                unsigned xl = (unsigned)__builtin_amdgcn_readlane(dlo, i);
                unsigned xh = (unsigned)__builtin_amdgcn_readlane(dhi, i);
                u64 di = ((u64)xh << 32) | (u64)xl;
                r |= di;
                u64 x = avail & ~di;
                avail = x & (x - 1);
            }
            keptb = ~r;
            if (lane == 0) rem[b] = r;
        } else if (wave <= 11) {
            // pull: OR of previously-kept rows' suppression of word nb
            if (nb < W) {
                int col = (nb << 6) | lane;
                bool cv = col < V;
                float4 cb; if (cv) cb = cbox[col];
                bool s = false;
                for (int t = wave - 1; t < K; t += 11) {
                    int r_ = klidx[t];
                    float4 br = cbox[r_];     // broadcast within wave
                    if (cv) s = s | iou_gt_thr(br, cb);
                }
                u64 bal = __ballot(s);
                if (lane == 0 && bal)
                    atomicOr((unsigned long long*)&pullw[nb & 1], bal);
            }
        } else if (wave <= 13) {
            // nextw: rows of block b vs cols of block nb (col>row automatic)
            if (nb < W) {
                int half = wave - 12;
                int col = (nb << 6) | lane;
                bool cv = col < V;
                float4 cb; if (cv) cb = cbox[col];
                #pragma unroll 4
                for (int i = half * 32; i < half * 32 + 32; i++) {
                    int row = rb0 + i;
                    bool ok = false;
                    if (row < V) { float4 br = cbox[row]; ok = cv && iou_gt_thr(br, cb); }
                    u64 bal = __ballot(ok);
                    if (lane == 0) nextw[i] = bal;
                }
            }
        } else {
            // diag of block nb (intra-block, lane>i)
            if (nb < W) {
                int half = wave - 14;
                int col = (nb << 6) | lane;
                bool cv = col < V;
                float4 cb; if (cv) cb = cbox[col];
                #pragma unroll 4
                for (int i = half * 32; i < half * 32 + 32; i++) {
                    int row = (nb << 6) + i;
                    bool ok = false;
                    if (row < V) { float4 br = cbox[row]; ok = cv && (lane > i) && iou_gt_thr(br, cb); }
                    u64 bal = __ballot(ok);
                    if (lane == 0) diagb[(nb & 1) * 64 + i] = bal;
                }
            }
        }
        __syncthreads();
        // phase 2: new-kept contribution + bookkeeping (proven)
        if (wave == 0) {
            if (nb < W) {
                u64 t = ((keptb >> lane) & 1ull) ? nextw[lane] : 0ull;
                #pragma unroll
                for (int off = 1; off < 64; off <<= 1)
                    t |= __shfl_xor(t, off, 64);
                if (lane == 0 && t)
                    atomicOr((unsigned long long*)&pullw[nb & 1], t);
            }
            if ((keptb >> lane) & 1ull) {
                int pos = (int)__popcll(keptb & ((1ull << lane) - 1ull));
                klidx[K + pos] = rb0 + lane;
            }
            if (lane == 0) Ksh = K + (int)__popcll(keptb);
        } else if (tid == 64) {
            pullw[b & 1] = 0;         // consumed; clean slot for block b+2
        }
        __syncthreads();
    }

    // ---- P7: scatter kept rows into (pre-zeroed) out ----
    for (int k = tid; k < V; k += NT) {
        bool keep = !((rem[k >> 6] >> (k & 63)) & 1ull);
        if (keep) {
            int rk = vrank[k];
            float4 b = cbox[k];
            out[rk * 5 + 0] = b.x;
            out[rk * 5 + 1] = b.y;
            out[rk * 5 + 2] = b.z;
            out[rk * 5 + 3] = b.w;
            out[rk * 5 + 4] = cscore[k];
            out[NPROP * 5 + rk] = 1.0f;
        }
    }
}

extern "C" void kernel_launch(void* const* d_in, const int* in_sizes, int n_in,
                              void* d_out, int out_size, void* d_ws, size_t ws_size,
                              hipStream_t stream) {
    const float* boxes  = (const float*)d_in[0];
    const float* scores = (const float*)d_in[1];
    const float* img    = (const float*)d_in[2];
    char* ws = (char*)d_ws;
    float4* cbox   = (float4*)(ws + 0);        // 128 KiB
    float*  cscore = (float*)(ws + 131072);    //  32 KiB
    int*    vrank  = (int*)(ws + 163840);      //  32 KiB
    float* out = (float*)d_out;

    k_all<<<1, NT, SMEM_BYTES, stream>>>(boxes, scores, img, cbox, cscore, vrank, out);
}

// Round 25
// 49.705 us; speedup vs baseline: 2.6727x; 2.6727x over previous
//
#include <hip/hip_runtime.h>

#define NPROP 8192
#define NT 1024
typedef unsigned long long u64;

__device__ __forceinline__ int bucket_of(float s) {
    int b = (int)(s * 8192.0f);   // exact: *2^13 is an exponent shift
    return b < 0 ? 0 : (b > NPROP - 1 ? NPROP - 1 : b);
}

__device__ __forceinline__ bool iou_gt_thr(float4 a, float4 b) {
    float areaA = (a.z - a.x) * (a.w - a.y);
    float areaB = (b.z - b.x) * (b.w - b.y);
    float lx = fmaxf(a.x, b.x), ly = fmaxf(a.y, b.y);
    float rx = fminf(a.z, b.z), ry = fminf(a.w, b.w);
    float w = fmaxf(rx - lx, 0.0f), h = fmaxf(ry - ly, 0.0f);
    float inter = w * h;
    float uni = areaA + areaB - inter;
    float iou = inter / fmaxf(uni, 1e-6f);
    return iou > 0.3f;
}

// K1: validity + packed hist + scan + scatter + rank, all LDS-internal.
// LDS carve (dynamic 98304 B): hist int[8192] | pref u32[8192] | tmp int[8192]
#define SMEM1 98304
__global__ __launch_bounds__(NT)
void k_sort1rank(const float* __restrict__ boxes, const float* __restrict__ scores,
                 const float* __restrict__ img,
                 float4* __restrict__ cbox, float* __restrict__ cscore,
                 int* __restrict__ vrank, int* __restrict__ meta) {
    extern __shared__ char smem[];
    int*      hist = (int*)smem;
    unsigned* pref = (unsigned*)(smem + 32768);
    int*      tmp  = (int*)(smem + 65536);
    __shared__ int wsum[16], wexcl[16];
    __shared__ int metaV[4];
    const int tid = threadIdx.x, lane = tid & 63, wave = tid >> 6;

    #pragma unroll
    for (int u = 0; u < 8; u++) hist[tid * 8 + u] = 0;
    __syncthreads();

    // P1: load own 8 proposals (coalesced), validity, packed histogram
    float ix1 = img[0], iy1 = img[1], ix2 = img[2], iy2 = img[3];
    float img_area = (ix2 - ix1) * (iy2 - iy1);
    float ss[8]; int bk[8], vf[8];
    #pragma unroll
    for (int u = 0; u < 8; u++) {
        int p = u * NT + tid;
        float s = scores[p];
        float4 bx = reinterpret_cast<const float4*>(boxes)[p];
        float w = bx.z - bx.x, h = bx.w - bx.y;
        float ratio = w / (h + 1e-12f);
        bool vs = (ratio > 0.25f) && (ratio < 4.0f);
        float lx = fmaxf(ix1, bx.x), ly = fmaxf(iy1, bx.y);
        float rx = fminf(ix2, bx.z), ry = fminf(iy2, bx.w);
        float iw = fmaxf(rx - lx, 0.0f), ih = fmaxf(ry - ly, 0.0f);
        float iof = (iw * ih) / fmaxf(img_area, 1e-6f);
        ss[u] = s;
        bk[u] = bucket_of(s);
        vf[u] = (vs && (iof > 0.01f) && (s > 0.85f)) ? 1 : 0;
        atomicAdd(&hist[bk[u]], 1 + (vf[u] << 16));
    }
    __syncthreads();

    // P2: packed exclusive scan over 8192 buckets
    int h[8]; int tot = 0;
    #pragma unroll
    for (int u = 0; u < 8; u++) { h[u] = hist[tid * 8 + u]; tot += h[u]; }
    int incl = tot;
    #pragma unroll
    for (int off = 1; off < 64; off <<= 1) {
        int n = __shfl_up(incl, off, 64);
        if (lane >= off) incl += n;
    }
    if (lane == 63) wsum[wave] = incl;
    __syncthreads();
    if (tid == 0) {
        int acc = 0;
        #pragma unroll
        for (int w = 0; w < 16; w++) { int t = wsum[w]; wexcl[w] = acc; acc += t; }
        int Vraw = acc >> 16;
        int V = Vraw == 0 ? 1 : Vraw;
        metaV[0] = V; metaV[1] = (V + 63) >> 6; metaV[2] = Vraw;
        meta[0] = V; meta[1] = (V + 63) >> 6; meta[2] = Vraw;
    }
    __syncthreads();
    int run = wexcl[wave] + (incl - tot);     // packed prefix
    int runA = run & 0xffff;                  // all-count prefix (allocator)
    #pragma unroll
    for (int u = 0; u < 8; u++) { pref[tid * 8 + u] = (unsigned)run; run += h[u]; }
    __syncthreads();   // all hist reads done before overwrite as allocator
    #pragma unroll
    for (int u = 0; u < 8; u++) { hist[tid * 8 + u] = runA; runA += h[u] & 0xffff; }
    __syncthreads();

    // P3: scatter into bucket-grouped LDS order (validity-tagged)
    #pragma unroll
    for (int u = 0; u < 8; u++) {
        int slot = atomicAdd(&hist[bk[u]], 1);
        tmp[slot] = (u * NT + tid) | (vf[u] << 31);
    }
    __syncthreads();

    const int Vraw = metaV[2];

    // P4: rank own proposals; valid ones materialize cbox/cscore/vrank
    #pragma unroll
    for (int u = 0; u < 8; u++) {
        int p = u * NT + tid;
        u64 key = ((u64)__float_as_uint(ss[u]) << 32) | (u64)(unsigned)(NPROP - 1 - p);
        int b = bk[u];
        unsigned pb = pref[b];
        int lo = (int)(pb & 0xffffu), vlo = (int)(pb >> 16);
        int hi = (b < NPROP - 1) ? (int)(pref[b + 1] & 0xffffu) : NPROP;
        int cnt = 0, vcnt = 0;
        for (int q = lo; q < hi; q++) {
            int jp = tmp[q];
            int j = jp & 0xffff;
            int vfj = (int)((unsigned)jp >> 31);
            u64 kj = ((u64)__float_as_uint(scores[j]) << 32) | (u64)(unsigned)(NPROP - 1 - j);
            int less = (kj < key) ? 1 : 0;
            cnt += less; vcnt += less & vfj;
        }
        int rank = NPROP - 1 - (lo + cnt);    // descending, stable
        if (vf[u]) {
            int cpos = Vraw - 1 - (vlo + vcnt);
            float4 bx = reinterpret_cast<const float4*>(boxes)[p];
            cbox[cpos] = bx; cscore[cpos] = ss[u]; vrank[cpos] = rank;
        } else if (Vraw == 0 && rank == 0) {  // fallback: keep top-scoring only
            float4 bx = reinterpret_cast<const float4*>(boxes)[p];
            cbox[0] = bx; cscore[0] = ss[u]; vrank[0] = 0;
        }
    }
}

// K2: zero the output buffer + build suppression mask (column-major mask[w*VP+r])
__global__ __launch_bounds__(256)
void k_mask(const float4* __restrict__ cbox, const int* __restrict__ meta,
            u64* __restrict__ mask, float* __restrict__ out) {
    int gid = blockIdx.x * 256 + threadIdx.x;
    if (gid < (NPROP * 6) / 4)                // 12288 float4 = 8192*(5+1) floats
        reinterpret_cast<float4*>(out)[gid] = make_float4(0.f, 0.f, 0.f, 0.f);
    const int V = meta[0], W = meta[1];
    const int VP = W << 6;
    const int lane = threadIdx.x & 63;
    int gw = blockIdx.x * 4 + (threadIdx.x >> 6);
    for (int r = gw; r < V; r += 1024) {
        float4 br = cbox[r];
        for (int w = (r >> 6); w < W; w++) {
            int col = w * 64 + lane;
            bool ok = (col < V) && (col > r) && iou_gt_thr(br, cbox[col]);
            u64 bal = __ballot(ok);
            if (lane == 0) mask[(u64)w * VP + r] = bal;
        }
    }
}

// K3: pipelined pull-resolve + direct kept-row scatter to out
__global__ __launch_bounds__(NT)
void k_resolve(const u64* __restrict__ mask, const int* __restrict__ meta,
               const float4* __restrict__ cbox, const float* __restrict__ cscore,
               const int* __restrict__ vrank, float* __restrict__ out) {
    __shared__ u64 rem[NPROP / 64];   // 1 KiB
    __shared__ u64 diagb[2][64];      // diag words, ping-pong
    __shared__ u64 nextw[64];         // rows of block b, col-word b+1
    __shared__ u64 pullw[2];
    __shared__ int klidx[NPROP];      // kept-row indices
    __shared__ int Ksh;
    const int V = meta[0], W = meta[1];
    const int VP = W << 6;
    const int tid = threadIdx.x, lane = tid & 63, wave = tid >> 6;

    for (int w = tid; w < NPROP / 64; w += NT) {
        int b0 = w * 64; u64 m;
        if (b0 >= V) m = ~0ull;
        else if (b0 + 64 <= V) m = 0ull;
        else m = (~0ull) << (V - b0);
        rem[w] = m;
    }
    if (tid == 0) { Ksh = 0; pullw[0] = 0; pullw[1] = 0; }
    if (wave == 15) diagb[0][lane] = (lane < V) ? mask[lane] : 0ull;
    __syncthreads();

    for (int b = 0; b < W; b++) {
        const int rb0 = b << 6;
        const int nb = b + 1;
        const int K = Ksh;            // kept through block b-1 (stable this phase)
        u64 keptb = 0;
        // ---- phase 1: chain(b) on wave 0 || prefetch for b+1 on waves 1..15 ----
        if (wave == 0) {
            u64 d = diagb[b & 1][lane];
            int dlo = (int)(unsigned)(d & 0xffffffffull);
            int dhi = (int)(unsigned)(d >> 32);
            u64 r0 = rem[b] | pullw[b & 1];
            unsigned rl_ = (unsigned)__builtin_amdgcn_readfirstlane((int)(unsigned)(r0 & 0xffffffffull));
            unsigned rh_ = (unsigned)__builtin_amdgcn_readfirstlane((int)(unsigned)(r0 >> 32));
            u64 r = ((u64)rh_ << 32) | (u64)rl_;
            u64 avail = ~r;           // candidates (pad bits pre-removed)
            while (avail) {
                int i = (int)__builtin_ctzll(avail);          // lowest candidate -> KEPT
                unsigned xl = (unsigned)__builtin_amdgcn_readlane(dlo, i);
                unsigned xh = (unsigned)__builtin_amdgcn_readlane(dhi, i);
                u64 di = ((u64)xh << 32) | (u64)xl;
                r |= di;
                u64 x = avail & ~di;
                avail = x & (x - 1);
            }
            keptb = ~r;
            if (lane == 0) rem[b] = r;
        } else if (wave <= 13) {
            if (nb < W) {             // pull words of previously-kept rows
                u64 myor = 0;
                for (int t = (wave - 1) * 64 + lane; t < K; t += 13 * 64)
                    myor |= mask[(u64)nb * VP + klidx[t]];
                #pragma unroll
                for (int off = 1; off < 64; off <<= 1)
                    myor |= __shfl_xor(myor, off, 64);
                if (lane == 0 && myor)
                    atomicOr((unsigned long long*)&pullw[nb & 1], myor);
            }
        } else if (wave == 14) {
            if (nb < W) {             // rows of block b -> their word nb (coalesced)
                int r_ = rb0 + lane;
                nextw[lane] = (r_ < V) ? mask[(u64)nb * VP + r_] : 0ull;
            }
        } else {                      // wave 15: diag of block nb (coalesced)
            if (nb < W) {
                int r_ = (nb << 6) + lane;
                diagb[nb & 1][lane] = (r_ < V) ? mask[(u64)nb * VP + r_] : 0ull;
            }
        }
        __syncthreads();
        // ---- phase 2: new-kept contribution + bookkeeping ----
        if (wave == 0) {
            if (nb < W) {
                u64 t = ((keptb >> lane) & 1ull) ? nextw[lane] : 0ull;
                #pragma unroll
                for (int off = 1; off < 64; off <<= 1)
                    t |= __shfl_xor(t, off, 64);
                if (lane == 0 && t)
                    atomicOr((unsigned long long*)&pullw[nb & 1], t);
            }
            if ((keptb >> lane) & 1ull) {
                int pos = (int)__popcll(keptb & ((1ull << lane) - 1ull));
                klidx[K + pos] = rb0 + lane;
            }
            if (lane == 0) Ksh = K + (int)__popcll(keptb);
        } else if (tid == 64) {
            pullw[b & 1] = 0;         // consumed; clean slot for block b+2
        }
        __syncthreads();
    }

    // ---- scatter kept rows into (pre-zeroed) out ----
    for (int k = tid; k < V; k += NT) {
        bool keep = !((rem[k >> 6] >> (k & 63)) & 1ull);
        if (keep) {
            int rk = vrank[k];
            float4 b = cbox[k];
            out[rk * 5 + 0] = b.x;
            out[rk * 5 + 1] = b.y;
            out[rk * 5 + 2] = b.z;
            out[rk * 5 + 3] = b.w;
            out[rk * 5 + 4] = cscore[k];
            out[NPROP * 5 + rk] = 1.0f;
        }
    }
}

extern "C" void kernel_launch(void* const* d_in, const int* in_sizes, int n_in,
                              void* d_out, int out_size, void* d_ws, size_t ws_size,
                              hipStream_t stream) {
    const float* boxes  = (const float*)d_in[0];
    const float* scores = (const float*)d_in[1];
    const float* img    = (const float*)d_in[2];
    char* ws = (char*)d_ws;
    float*  cscore = (float*)(ws + 0);         //  32 KiB
    float4* cbox   = (float4*)(ws + 32768);    // 128 KiB
    int*    vrank  = (int*)(ws + 163840);      //  32 KiB
    int*    meta   = (int*)(ws + 196608);      //   1 KiB
    u64*    mask   = (u64*)(ws + 197632);      //  W*VP*8 B (~200 KiB realistic)
    float* out = (float*)d_out;

    k_sort1rank<<<1, NT, SMEM1, stream>>>(boxes, scores, img, cbox, cscore, vrank, meta);
    k_mask<<<256, 256, 0, stream>>>(cbox, meta, mask, out);
    k_resolve<<<1, NT, 0, stream>>>(mask, meta, cbox, cscore, vrank, out);
}

// Round 26
// 44.529 us; speedup vs baseline: 2.9833x; 1.1162x over previous
//
#include <hip/hip_runtime.h>

#define NPROP 8192
#define NT 1024
typedef unsigned long long u64;

__device__ __forceinline__ int bucket_of(float s) {
    int b = (int)(s * 8192.0f);   // exact: *2^13 is an exponent shift
    return b < 0 ? 0 : (b > NPROP - 1 ? NPROP - 1 : b);
}

__device__ __forceinline__ bool iou_gt_thr(float4 a, float4 b) {
    float areaA = (a.z - a.x) * (a.w - a.y);
    float areaB = (b.z - b.x) * (b.w - b.y);
    float lx = fmaxf(a.x, b.x), ly = fmaxf(a.y, b.y);
    float rx = fminf(a.z, b.z), ry = fminf(a.w, b.w);
    float w = fmaxf(rx - lx, 0.0f), h = fmaxf(ry - ly, 0.0f);
    float inter = w * h;
    float uni = areaA + areaB - inter;
    float iou = inter / fmaxf(uni, 1e-6f);
    return iou > 0.3f;
}

// K1: validity + packed LDS histogram (all | valid<<16) + scan + tagged scatter
__global__ __launch_bounds__(NT)
void k_sort1(const float* __restrict__ boxes, const float* __restrict__ scores,
             const float* __restrict__ img,
             unsigned* __restrict__ prefP, int* __restrict__ tmp_idx,
             int* __restrict__ meta) {
    __shared__ int hist[NPROP];   // 32 KiB: packed counts -> allocator
    __shared__ int wsum[16], wexcl[16];
    const int tid = threadIdx.x, lane = tid & 63, wave = tid >> 6;
    #pragma unroll
    for (int u = 0; u < 8; u++) hist[tid * 8 + u] = 0;
    __syncthreads();
    float ix1 = img[0], iy1 = img[1], ix2 = img[2], iy2 = img[3];
    float img_area = (ix2 - ix1) * (iy2 - iy1);
    float ss[8]; int pp[8], bk[8], vf[8];
    #pragma unroll
    for (int u = 0; u < 8; u++) {
        int p = u * NT + tid;                 // coalesced per-u
        pp[u] = p;
        float s = scores[p];
        float4 bx = reinterpret_cast<const float4*>(boxes)[p];
        float w = bx.z - bx.x, h = bx.w - bx.y;
        float ratio = w / (h + 1e-12f);
        bool vs = (ratio > 0.25f) && (ratio < 4.0f);
        float lx = fmaxf(ix1, bx.x), ly = fmaxf(iy1, bx.y);
        float rx = fminf(ix2, bx.z), ry = fminf(iy2, bx.w);
        float iw = fmaxf(rx - lx, 0.0f), ih = fmaxf(ry - ly, 0.0f);
        float iof = (iw * ih) / fmaxf(img_area, 1e-6f);
        ss[u] = s;
        bk[u] = bucket_of(s);
        vf[u] = (vs && (iof > 0.01f) && (s > 0.85f)) ? 1 : 0;
        atomicAdd(&hist[bk[u]], 1 + (vf[u] << 16));
    }
    __syncthreads();
    int h[8]; int tot = 0;
    #pragma unroll
    for (int u = 0; u < 8; u++) { h[u] = hist[tid * 8 + u]; tot += h[u]; }
    int incl = tot;
    #pragma unroll
    for (int off = 1; off < 64; off <<= 1) {
        int n = __shfl_up(incl, off, 64);
        if (lane >= off) incl += n;
    }
    if (lane == 63) wsum[wave] = incl;
    __syncthreads();
    if (tid == 0) {
        int acc = 0;
        #pragma unroll
        for (int w = 0; w < 16; w++) { int t = wsum[w]; wexcl[w] = acc; acc += t; }
        int Vraw = acc >> 16;                 // total valid
        int V = Vraw == 0 ? 1 : Vraw;
        meta[0] = V;
        meta[1] = (V + 63) >> 6;
        meta[2] = Vraw;
    }
    __syncthreads();
    int run = wexcl[wave] + (incl - tot);     // packed prefix
    int runA = run & 0xffff;                  // all-count prefix (allocator)
    #pragma unroll
    for (int u = 0; u < 8; u++) { prefP[tid * 8 + u] = (unsigned)run; run += h[u]; }
    __syncthreads();   // all hist reads done before overwrite as allocator
    #pragma unroll
    for (int u = 0; u < 8; u++) { hist[tid * 8 + u] = runA; runA += h[u] & 0xffff; }
    __syncthreads();
    #pragma unroll
    for (int u = 0; u < 8; u++) {
        int slot = atomicAdd(&hist[bk[u]], 1);
        tmp_idx[slot] = pp[u] | (vf[u] << 31);   // validity-tagged index
    }
}

// K2: exact stable rank; ONLY valid proposals materialize (cbox/cscore/vrank)
__global__ void k_rank(const float* __restrict__ scores, const float* __restrict__ boxes,
                       const int* __restrict__ tmp_idx, const unsigned* __restrict__ prefP,
                       const int* __restrict__ meta,
                       float4* __restrict__ cbox, float* __restrict__ cscore,
                       int* __restrict__ vrank) {
    int p = blockIdx.x * blockDim.x + threadIdx.x;
    int ip = tmp_idx[p];
    int i = ip & 0xffff;
    bool vf = ip < 0;
    int Vraw = meta[2];
    float s = scores[i];
    u64 key = ((u64)__float_as_uint(s) << 32) | (u64)(unsigned)(NPROP - 1 - i);
    int b = bucket_of(s);
    unsigned pb = prefP[b];
    int lo = (int)(pb & 0xffffu), vlo = (int)(pb >> 16);
    int hi = (b < NPROP - 1) ? (int)(prefP[b + 1] & 0xffffu) : NPROP;
    int cnt = 0, vcnt = 0;
    for (int q = lo; q < hi; q++) {
        int jp = tmp_idx[q];
        int j = jp & 0xffff;
        int vfj = (int)((unsigned)jp >> 31);
        u64 kj = ((u64)__float_as_uint(scores[j]) << 32) | (u64)(unsigned)(NPROP - 1 - j);
        int less = (kj < key) ? 1 : 0;
        cnt += less; vcnt += less & vfj;
    }
    int rank = NPROP - 1 - (lo + cnt);        // descending, stable
    if (vf) {
        int cpos = Vraw - 1 - (vlo + vcnt);   // compact pos among valid (descending)
        float4 bx = reinterpret_cast<const float4*>(boxes)[i];
        cbox[cpos] = bx;
        cscore[cpos] = s;
        vrank[cpos] = rank;
    } else if (Vraw == 0 && rank == 0) {      // fallback: keep top-scoring only
        float4 bx = reinterpret_cast<const float4*>(boxes)[i];
        cbox[0] = bx;
        cscore[0] = s;
        vrank[0] = 0;
    }
}

// K3: zero the output buffer + build suppression mask (column-major mask[w*VP+r])
__global__ __launch_bounds__(256)
void k_mask(const float4* __restrict__ cbox, const int* __restrict__ meta,
            u64* __restrict__ mask, float* __restrict__ out) {
    int gid = blockIdx.x * 256 + threadIdx.x;
    if (gid < (NPROP * 6) / 4)                // 12288 float4 = 8192*(5+1) floats
        reinterpret_cast<float4*>(out)[gid] = make_float4(0.f, 0.f, 0.f, 0.f);
    const int V = meta[0], W = meta[1];
    const int VP = W << 6;
    const int lane = threadIdx.x & 63;
    int gw = blockIdx.x * 4 + (threadIdx.x >> 6);
    for (int r = gw; r < V; r += 1024) {
        float4 br = cbox[r];
        for (int w = (r >> 6); w < W; w++) {
            int col = w * 64 + lane;
            bool ok = (col < V) && (col > r) && iou_gt_thr(br, cbox[col]);
            u64 bal = __ballot(ok);
            if (lane == 0) mask[(u64)w * VP + r] = bal;
        }
    }
}

// K4: pipelined pull-resolve + direct kept-row scatter to out
__global__ __launch_bounds__(NT)
void k_resolve(const u64* __restrict__ mask, const int* __restrict__ meta,
               const float4* __restrict__ cbox, const float* __restrict__ cscore,
               const int* __restrict__ vrank, float* __restrict__ out) {
    __shared__ u64 rem[NPROP / 64];   // 1 KiB
    __shared__ u64 diagb[2][64];      // diag words, ping-pong
    __shared__ u64 nextw[64];         // rows of block b, col-word b+1
    __shared__ u64 pullw[2];
    __shared__ int klidx[NPROP];      // kept-row indices
    __shared__ int Ksh;
    const int V = meta[0], W = meta[1];
    const int VP = W << 6;
    const int tid = threadIdx.x, lane = tid & 63, wave = tid >> 6;

    for (int w = tid; w < NPROP / 64; w += NT) {
        int b0 = w * 64; u64 m;
        if (b0 >= V) m = ~0ull;
        else if (b0 + 64 <= V) m = 0ull;
        else m = (~0ull) << (V - b0);
        rem[w] = m;
    }
    if (tid == 0) { Ksh = 0; pullw[0] = 0; pullw[1] = 0; }
    if (wave == 15) diagb[0][lane] = (lane < V) ? mask[lane] : 0ull;
    __syncthreads();

    for (int b = 0; b < W; b++) {
        const int rb0 = b << 6;
        const int nb = b + 1;
        const int K = Ksh;            // kept through block b-1 (stable this phase)
        u64 keptb = 0;
        // ---- phase 1: chain(b) on wave 0 || prefetch for b+1 on waves 1..15 ----
        if (wave == 0) {
            u64 d = diagb[b & 1][lane];
            int dlo = (int)(unsigned)(d & 0xffffffffull);
            int dhi = (int)(unsigned)(d >> 32);
            u64 r0 = rem[b] | pullw[b & 1];
            unsigned rl_ = (unsigned)__builtin_amdgcn_readfirstlane((int)(unsigned)(r0 & 0xffffffffull));
            unsigned rh_ = (unsigned)__builtin_amdgcn_readfirstlane((int)(unsigned)(r0 >> 32));
            u64 r = ((u64)rh_ << 32) | (u64)rl_;
            u64 avail = ~r;           // candidates (pad bits pre-removed)
            while (avail) {
                int i = (int)__builtin_ctzll(avail);          // lowest candidate -> KEPT
                unsigned xl = (unsigned)__builtin_amdgcn_readlane(dlo, i);
                unsigned xh = (unsigned)__builtin_amdgcn_readlane(dhi, i);
                u64 di = ((u64)xh << 32) | (u64)xl;
                r |= di;
                u64 x = avail & ~di;
                avail = x & (x - 1);
            }
            keptb = ~r;
            if (lane == 0) rem[b] = r;
        } else if (wave <= 13) {
            if (nb < W) {             // pull words of previously-kept rows
                u64 myor = 0;
                for (int t = (wave - 1) * 64 + lane; t < K; t += 13 * 64)
                    myor |= mask[(u64)nb * VP + klidx[t]];
                #pragma unroll
                for (int off = 1; off < 64; off <<= 1)
                    myor |= __shfl_xor(myor, off, 64);
                if (lane == 0 && myor)
                    atomicOr((unsigned long long*)&pullw[nb & 1], myor);
            }
        } else if (wave == 14) {
            if (nb < W) {             // rows of block b -> their word nb (coalesced)
                int r_ = rb0 + lane;
                nextw[lane] = (r_ < V) ? mask[(u64)nb * VP + r_] : 0ull;
            }
        } else {                      // wave 15: diag of block nb (coalesced)
            if (nb < W) {
                int r_ = (nb << 6) + lane;
                diagb[nb & 1][lane] = (r_ < V) ? mask[(u64)nb * VP + r_] : 0ull;
            }
        }
        __syncthreads();
        // ---- phase 2: new-kept contribution + bookkeeping ----
        if (wave == 0) {
            if (nb < W) {
                u64 t = ((keptb >> lane) & 1ull) ? nextw[lane] : 0ull;
                #pragma unroll
                for (int off = 1; off < 64; off <<= 1)
                    t |= __shfl_xor(t, off, 64);
                if (lane == 0 && t)
                    atomicOr((unsigned long long*)&pullw[nb & 1], t);
            }
            if ((keptb >> lane) & 1ull) {
                int pos = (int)__popcll(keptb & ((1ull << lane) - 1ull));
                klidx[K + pos] = rb0 + lane;
            }
            if (lane == 0) Ksh = K + (int)__popcll(keptb);
        } else if (tid == 64) {
            pullw[b & 1] = 0;         // consumed; clean slot for block b+2
        }
        __syncthreads();
    }

    // ---- scatter kept rows into (pre-zeroed) out ----
    for (int k = tid; k < V; k += NT) {
        bool keep = !((rem[k >> 6] >> (k & 63)) & 1ull);
        if (keep) {
            int rk = vrank[k];
            float4 b = cbox[k];
            out[rk * 5 + 0] = b.x;
            out[rk * 5 + 1] = b.y;
            out[rk * 5 + 2] = b.z;
            out[rk * 5 + 3] = b.w;
            out[rk * 5 + 4] = cscore[k];
            out[NPROP * 5 + rk] = 1.0f;
        }
    }
}

extern "C" void kernel_launch(void* const* d_in, const int* in_sizes, int n_in,
                              void* d_out, int out_size, void* d_ws, size_t ws_size,
                              hipStream_t stream) {
    const float* boxes  = (const float*)d_in[0];
    const float* scores = (const float*)d_in[1];
    const float* img    = (const float*)d_in[2];
    char* ws = (char*)d_ws;
    unsigned* prefP  = (unsigned*)(ws + 0);      // 32 KiB
    int*    tmp_idx  = (int*)(ws + 32768);       // 32 KiB
    float*  cscore   = (float*)(ws + 65536);     // 32 KiB
    float4* cbox     = (float4*)(ws + 98304);    // 128 KiB
    int*    vrank    = (int*)(ws + 229376);      // 32 KiB
    int*    meta     = (int*)(ws + 262144);      // 1 KiB
    u64*    mask     = (u64*)(ws + 263168);      // W*VP*8 B (~200 KiB realistic)
    float* out = (float*)d_out;

    k_sort1<<<1, NT, 0, stream>>>(boxes, scores, img, prefP, tmp_idx, meta);
    k_rank<<<32, 256, 0, stream>>>(scores, boxes, tmp_idx, prefP, meta,
                                   cbox, cscore, vrank);
    k_mask<<<256, 256, 0, stream>>>(cbox, meta, mask, out);
    k_resolve<<<1, NT, 0, stream>>>(mask, meta, cbox, cscore, vrank, out);
}